// Round 5
// baseline (492.806 us; speedup 1.0000x reference)
//
#include <hip/hip_runtime.h>
#include <stdint.h>

#define NN 1024
#define FF 35
#define LIN_IN 1610
#define NB 16

typedef short short8 __attribute__((ext_vector_type(8)));
typedef float f32x4 __attribute__((ext_vector_type(4)));

__device__ __forceinline__ float leakyf(float x) { return fmaxf(x, 0.01f * x); }
__device__ __forceinline__ uint16_t to_bf16(float v) {
    return (uint16_t)((__float_as_uint(v) + 0x8000u) >> 16);
}

// ---------------------------------------------------------------- codes: s(float 0..4) -> u8
__global__ __launch_bounds__(256)
void codes_kernel(const float* __restrict__ s, uint8_t* __restrict__ codes, int n4) {
    int i = blockIdx.x * 256 + threadIdx.x;
    for (; i < n4; i += gridDim.x * 256) {
        float4 v = ((const float4*)s)[i];
        uchar4 c;
        c.x = (uint8_t)v.x; c.y = (uint8_t)v.y; c.z = (uint8_t)v.z; c.w = (uint8_t)v.w;
        ((uchar4*)codes)[i] = c;
    }
}

// ---------------------------------------------------------------- labels -> XT0 bf16 [16][48][1024] + XR0 f32
__global__ __launch_bounds__(256)
void labels_to_xt(const float* __restrict__ labels, uint16_t* __restrict__ XT0,
                  float* __restrict__ XR0)
{
    __shared__ float buf[256 * FF];
    const int s = blockIdx.x;
    const int i0 = blockIdx.y * 256;
    const float* src = labels + ((size_t)s * NN + i0) * FF;
    for (int t = threadIdx.x; t < 256 * FF; t += 256) buf[t] = src[t];
    __syncthreads();
    for (int f = 0; f < 48; ++f) {
        const int ii = threadIdx.x;
        float v = (f < FF) ? buf[ii * FF + f] : 0.f;
        size_t o = ((size_t)s * 48 + f) * 1024 + i0 + ii;
        XR0[o] = v;
        XT0[o] = to_bf16(v);
    }
}

// ---------------------------------------------------------------- one-hot A-fragment expansion
// Borrow-free per-byte zero detect (exact per-byte mask).
__device__ __forceinline__ short8 expand_onehot(uint2 cd, uint32_t dupK) {
    union { uint32_t u[4]; short8 v; } r;
#pragma unroll
    for (int h = 0; h < 2; ++h) {
        uint32_t d = h ? cd.y : cd.x;
        uint32_t y = d ^ dupK;
        uint32_t m = (~(((y & 0x7F7F7F7Fu) + 0x7F7F7F7Fu) | y)) & 0x80808080u;
        uint32_t m2 = m >> 7;                               // 0x01 at matched bytes
        r.u[h * 2 + 0] = ((m2 & 0xFFu) | ((m2 & 0xFF00u) << 8)) * 0x3F80u;
        r.u[h * 2 + 1] = (((m2 >> 16) & 0xFFu) | ((m2 >> 8) & 0xFF0000u)) * 0x3F80u;
    }
    return r.v;
}

// ---------------------------------------------------------------- WLC step as MFMA GEMM
// One chout per block: 64(M=i) x 48(N=f). 4 waves on M. K-loop 16 j-tiles x 4 k.
// Register prefetch pipeline: next tile's staging + code bytes load during MFMA phase.
__global__ __launch_bounds__(256, 2)
void wlc_gemm(const uint16_t* __restrict__ XT_in, const float* __restrict__ XR_in,
              uint16_t* __restrict__ XT_out, float* __restrict__ XR_out,
              const uint8_t* __restrict__ codes, const float* __restrict__ Kg,
              int t, int shift, int nch_in, int nch_out, int do_leaky)
{
    __shared__ __align__(16) uint16_t xs[48 * 64];

    const int s    = blockIdx.z;
    const int mt   = blockIdx.x;
    const int nt   = blockIdx.y;       // = chout
    const int tid  = threadIdx.x;
    const int wid  = tid >> 6;
    const int lane = tid & 63;
    const int i0   = mt * 64;
    const int inch = nt >> shift;
    const int kch  = nt & 1;

    // staging: 48 rows x 64 bf16 = 384 16B-units; 2 per thread (valid if u<384)
    const int u0 = tid, u1 = 256 + tid;
    const bool v1 = (u1 < 384);
    const int r0s = u0 >> 3, c80 = u0 & 7;
    const int r1s = u1 >> 3, c81 = u1 & 7;
    const uint16_t* src0 = XT_in + (((size_t)s * nch_in + inch) * 48 + r0s) * 1024 + c80 * 8;
    const uint16_t* src1 = XT_in + (((size_t)s * nch_in + inch) * 48 + r1s) * 1024 + c81 * 8;
    uint16_t* dst0 = &xs[r0s * 64 + ((c80 ^ (r0s & 7)) * 8)];
    uint16_t* dst1 = &xs[r1s * 64 + ((c81 ^ (r1s & 7)) * 8)];

    const uint8_t* cbase = codes + ((size_t)s << 20)
        + (size_t)(i0 + wid * 16 + (lane & 15)) * 1024 + ((lane >> 4) << 3);

    f32x4 acc[4][3];
#pragma unroll
    for (int k = 0; k < 4; ++k)
#pragma unroll
        for (int nf = 0; nf < 3; ++nf) acc[k][nf] = (f32x4){0.f, 0.f, 0.f, 0.f};

    // prefetch tile 0
    uint4 pre0 = *(const uint4*)(src0);
    uint4 pre1 = v1 ? *(const uint4*)(src1) : (uint4){0, 0, 0, 0};
    uint2 pcd0 = *(const uint2*)(cbase);
    uint2 pcd1 = *(const uint2*)(cbase + 32);

    for (int jt = 0; jt < 16; ++jt) {
        __syncthreads();                       // previous tile's reads done
        *(uint4*)dst0 = pre0;
        if (v1) *(uint4*)dst1 = pre1;
        __syncthreads();

        const uint2 cd0 = pcd0, cd1 = pcd1;
        if (jt < 15) {                         // prefetch next tile during compute
            const int j1 = (jt + 1) * 64;
            pre0 = *(const uint4*)(src0 + j1);
            if (v1) pre1 = *(const uint4*)(src1 + j1);
            pcd0 = *(const uint2*)(cbase + j1);
            pcd1 = *(const uint2*)(cbase + j1 + 32);
        }

        short8 bfr[3][2];
#pragma unroll
        for (int nf = 0; nf < 3; ++nf)
#pragma unroll
            for (int kk = 0; kk < 2; ++kk) {
                int n = nf * 16 + (lane & 15);
                int c8 = kk * 4 + (lane >> 4);
                bfr[nf][kk] = *(const short8*)&xs[n * 64 + ((c8 ^ (n & 7)) * 8)];
            }

#pragma unroll
        for (int k = 0; k < 4; ++k) {
            const uint32_t dupK = 0x01010101u * (k + 1);
#pragma unroll
            for (int kk = 0; kk < 2; ++kk) {
                short8 af = expand_onehot(kk ? cd1 : cd0, dupK);
#pragma unroll
                for (int nf = 0; nf < 3; ++nf)
                    acc[k][nf] = __builtin_amdgcn_mfma_f32_16x16x32_bf16(
                        af, bfr[nf][kk], acc[k][nf], 0, 0, 0);
            }
        }
    }

    // epilogue: fold Kt scales, residual, leaky, store f32 + bf16
    float sc[4][3];
#pragma unroll
    for (int nf = 0; nf < 3; ++nf) {
        int fnl = nf * 16 + (lane & 15);
#pragma unroll
        for (int k = 0; k < 4; ++k)
            sc[k][nf] = (fnl < FF) ? Kg[((kch * 2 + t) * 4 + k) * FF + fnl] : 0.f;
    }

#pragma unroll
    for (int nf = 0; nf < 3; ++nf) {
        int fnl = nf * 16 + (lane & 15);
        int irow = i0 + wid * 16 + ((lane >> 4) << 2);
        f32x4 rr = sc[0][nf] * acc[0][nf];
        rr += sc[1][nf] * acc[1][nf];
        rr += sc[2][nf] * acc[2][nf];
        rr += sc[3][nf] * acc[3][nf];
        size_t rb = (((size_t)s * nch_in + inch) * 48 + fnl) * 1024 + irow;
        float4 rd = *(const float4*)&XR_in[rb];
        float y0 = rr.x + rd.x, y1 = rr.y + rd.y, y2 = rr.z + rd.z, y3 = rr.w + rd.w;
        if (do_leaky) { y0 = leakyf(y0); y1 = leakyf(y1); y2 = leakyf(y2); y3 = leakyf(y3); }
        size_t ob = (((size_t)s * nch_out + nt) * 48 + fnl) * 1024 + irow;
        *(float4*)&XR_out[ob] = make_float4(y0, y1, y2, y3);
        ushort4 bv;
        bv.x = to_bf16(y0); bv.y = to_bf16(y1); bv.z = to_bf16(y2); bv.w = to_bf16(y3);
        *(ushort4*)&XT_out[ob] = bv;
    }
}

// ---------------------------------------------------------------- spp max over c2 (layout [s][c][48][1024])
__global__ __launch_bounds__(256)
void spp_max_kernel(const float* __restrict__ xr4, float* __restrict__ h0)
{
    const int gw   = (blockIdx.x * 256 + threadIdx.x) >> 6;
    const int lane = threadIdx.x & 63;
    if (gw >= NB * 4 * 385) return;
    const int s    = gw / (4 * 385);
    int rem        = gw - s * (4 * 385);
    const int c    = rem / 385;
    const int cell = rem - c * 385;

    int p1 = 1, base = 0;
    while (p1 < 10 && cell >= base + p1 * p1) { base += p1 * p1; ++p1; }
    const int ci = cell - base;

    int kh = (NN + p1 - 1) / p1;  int ph = kh * p1 - NN; if (ph * 2 > kh) ph = kh / 2;
    int kw = (FF + p1 - 1) / p1;  int pw = kw * p1 - FF; if (pw * 2 > kw) pw = kw / 2;
    const int ow = (FF + 2 * pw - kw) / kw + 1;
    const int oh = (NN + 2 * ph - kh) / kh + 1;
    if (ci >= oh * ow) return;

    const int r = ci / ow, cw = ci - r * ow;
    int r0 = r * kh - ph;  int r1 = r0 + kh; if (r1 > NN) r1 = NN; if (r0 < 0) r0 = 0;
    int c0 = cw * kw - pw; int c1 = c0 + kw; if (c1 > FF) c1 = FF; if (c0 < 0) c0 = 0;

    const float* bp = xr4 + ((size_t)s * 4 + c) * (48 * 1024);
    float m = -3.402823466e38f;
    for (int ff = c0; ff < c1; ++ff) {
        const float* rowp = bp + (size_t)ff * 1024;
        for (int ii = r0 + lane; ii < r1; ii += 64) m = fmaxf(m, rowp[ii]);
    }
#pragma unroll
    for (int o = 32; o >= 1; o >>= 1) m = fmaxf(m, __shfl_xor(m, o, 64));
    if (lane == 0) h0[(size_t)s * LIN_IN + c * 385 + cell] = m;
}

// ---------------------------------------------------------------- fused conv1+conv2+avg pools, strip x col-half form
// grid (30 strips, 2 col-halves, 16 images). 255 threads x 2 cols (thread 255 idle dup).
// All pool bin boundaries are multiples of 34 (rows) / 170 (cols within halves are
// whole p2 bins; p3 boundary 340/680 is even so a 2-col thread never straddles).
__global__ __launch_bounds__(256, 2)
void conv_pool_strip(const float* __restrict__ sM,
                     const float* __restrict__ cw1, const float* __restrict__ cb1,
                     const float* __restrict__ cw2, const float* __restrict__ cb2,
                     float* __restrict__ h0)
{
    __shared__ float bins[10];       // [5ch][2]: qa (low p3 bin), qb (high p3 bin)
    const int ss   = blockIdx.x;     // strip 0..29
    const int hh   = blockIdx.y;     // col half 0..1
    const int simg = blockIdx.z;     // image
    const int tid  = threadIdx.x;
    const int lane = tid & 63;
    const int r0   = ss * 34;
    const int rb2  = (ss >= 15);
    const int rb3  = ss / 10;

    if (tid < 10) bins[tid] = 0.f;
    __syncthreads();

    const int cb = hh * 510 + ((tid < 255) ? tid * 2 : 508);
    const float* sp = sM + (size_t)simg * (NN * NN) + cb;

    float w1r[18], w2r[90], b1r[2], b2r[5];
#pragma unroll
    for (int i = 0; i < 18; ++i) w1r[i] = cw1[i];
#pragma unroll
    for (int i = 0; i < 90; ++i) w2r[i] = cw2[i];
    b1r[0] = cb1[0]; b1r[1] = cb1[1];
#pragma unroll
    for (int i = 0; i < 5; ++i) b2r[i] = cb2[i];

    float sw[3][6];
    float z1w[3][2][4];
    float acc[5][2];
#pragma unroll
    for (int o = 0; o < 5; ++o) { acc[o][0] = 0.f; acc[o][1] = 0.f; }

#define LOADROW(slot, rabs) do { \
    const float* rp = sp + (size_t)(rabs) * NN; \
    float2 a0 = *(const float2*)(rp); \
    float2 a1 = *(const float2*)(rp + 2); \
    float2 a2 = *(const float2*)(rp + 4); \
    sw[slot][0]=a0.x; sw[slot][1]=a0.y; sw[slot][2]=a1.x; \
    sw[slot][3]=a1.y; sw[slot][4]=a2.x; sw[slot][5]=a2.y; } while(0)

#define Z1ROW(P) do { \
    _Pragma("unroll") for (int ch = 0; ch < 2; ++ch) { \
      _Pragma("unroll") for (int jj = 0; jj < 4; ++jj) { \
        float a = b1r[ch]; \
        _Pragma("unroll") for (int dc = 0; dc < 3; ++dc) { \
            a += sw[((P)+2)%3][jj+dc] * w1r[ch*9+0+dc]; \
            a += sw[(P)%3    ][jj+dc] * w1r[ch*9+3+dc]; \
            a += sw[((P)+1)%3][jj+dc] * w1r[ch*9+6+dc]; } \
        z1w[((P)+2)%3][ch][jj] = leakyf(a); } } } while(0)

#define Z2ROW(P) do { \
    _Pragma("unroll") for (int o = 0; o < 5; ++o) { \
      _Pragma("unroll") for (int j = 0; j < 2; ++j) { \
        float a = b2r[o]; \
        _Pragma("unroll") for (int ich = 0; ich < 2; ++ich) { \
          _Pragma("unroll") for (int dc = 0; dc < 3; ++dc) { \
            a += z1w[(P)%3    ][ich][j+dc] * w2r[(o*2+ich)*9+0+dc]; \
            a += z1w[((P)+1)%3][ich][j+dc] * w2r[(o*2+ich)*9+3+dc]; \
            a += z1w[((P)+2)%3][ich][j+dc] * w2r[(o*2+ich)*9+6+dc]; } } \
        acc[o][j] += leakyf(a); } } } while(0)

    LOADROW(0, r0 + 0);
    LOADROW(1, r0 + 1);
    LOADROW(2, r0 + 2);
    Z1ROW(1);
    LOADROW(0, r0 + 3);
    Z1ROW(2);

#pragma unroll 1
    for (int rr = 0; rr < 33; rr += 3) {
        LOADROW(1, r0 + rr + 4); Z1ROW(0); Z2ROW(0);
        LOADROW(2, r0 + rr + 5); Z1ROW(1); Z2ROW(1);
        LOADROW(0, r0 + rr + 6); Z1ROW(2); Z2ROW(2);
    }
    LOADROW(1, r0 + 37); Z1ROW(0); Z2ROW(0);   // z2 row 33

#undef LOADROW
#undef Z1ROW
#undef Z2ROW

    if (tid == 255) {
#pragma unroll
        for (int o = 0; o < 5; ++o) { acc[o][0] = 0.f; acc[o][1] = 0.f; }
    }

    const int thr = hh ? 680 : 340;        // p3 boundary inside this half (even)
    const bool sideA = cb < thr;
#pragma unroll
    for (int o = 0; o < 5; ++o) {
        float v = acc[o][0] + acc[o][1];
        float qa = sideA ? v : 0.f;
        float qb = sideA ? 0.f : v;
#pragma unroll
        for (int d = 32; d >= 1; d >>= 1) {
            qa += __shfl_xor(qa, d, 64);
            qb += __shfl_xor(qb, d, 64);
        }
        if (lane == 0) {
            atomicAdd(&bins[o * 2 + 0], qa);
            atomicAdd(&bins[o * 2 + 1], qb);
        }
    }
    __syncthreads();
    if (tid < 10) {
        int o = tid >> 1, w = tid & 1;
        atomicAdd(h0 + (size_t)simg * LIN_IN + 1540 + o * 14 + 5 + rb3 * 3 + hh + w, bins[tid]);
    }
    if (tid < 5) {
        float t1 = bins[tid * 2] + bins[tid * 2 + 1];
        float* dst = h0 + (size_t)simg * LIN_IN + 1540 + tid * 14;
        atomicAdd(dst, t1);
        atomicAdd(dst + 1 + rb2 * 2 + hh, t1);
    }
}

__global__ __launch_bounds__(256)
void stru_div_kernel(float* __restrict__ h0)
{
    const int i = blockIdx.x * 256 + threadIdx.x;
    if (i >= NB * 5 * 14) return;
    const int s = i / (5 * 14);
    const int rest = i - s * (5 * 14);
    const int within = rest % 14;
    const float d = (within == 0) ? (1.f / (1020.f * 1020.f))
                  : (within < 5)  ? (1.f / (510.f * 510.f))
                                  : (1.f / (340.f * 340.f));
    h0[(size_t)s * LIN_IN + 1540 + rest] *= d;
}

// ---------------------------------------------------------------- FC
__global__ __launch_bounds__(256)
void fc_kernel(const float* __restrict__ in, const float* __restrict__ W,
               const float* __restrict__ bias, float* __restrict__ out,
               int K, int Nout, int do_leaky)
{
    const int o = (blockIdx.x * 256 + threadIdx.x) >> 6;
    const int lane = threadIdx.x & 63;
    if (o >= Nout) return;
    const float* wrow = W + (size_t)o * K;
    float acc[16];
#pragma unroll
    for (int b = 0; b < 16; ++b) acc[b] = 0.f;
    for (int k0 = 0; k0 < K; k0 += 64) {
        const int kk = k0 + lane;
        const bool in_r = kk < K;
        const float wv = in_r ? wrow[kk] : 0.f;
#pragma unroll
        for (int b = 0; b < 16; ++b) {
            const float hv = in_r ? in[(size_t)b * K + kk] : 0.f;
            acc[b] += wv * hv;
        }
    }
    float res = 0.f;
#pragma unroll
    for (int b = 0; b < 16; ++b) {
        float v = acc[b];
#pragma unroll
        for (int od = 32; od >= 1; od >>= 1) v += __shfl_xor(v, od, 64);
        if (lane == b) res = v;
    }
    if (lane < 16) {
        const float y = res + bias[o];
        out[(size_t)lane * Nout + o] = do_leaky ? leakyf(y) : y;
    }
}

// ---------------------------------------------------------------- launch
extern "C" void kernel_launch(void* const* d_in, const int* in_sizes, int n_in,
                              void* d_out, int out_size, void* d_ws, size_t ws_size,
                              hipStream_t stream)
{
    const float* labels = (const float*)d_in[0];
    const float* sM     = (const float*)d_in[1];
    const float* K1     = (const float*)d_in[2];
    const float* K2     = (const float*)d_in[3];
    const float* cw1    = (const float*)d_in[4];
    const float* cb1    = (const float*)d_in[5];
    const float* cw2    = (const float*)d_in[6];
    const float* cb2    = (const float*)d_in[7];
    const float* W1     = (const float*)d_in[8];
    const float* b1     = (const float*)d_in[9];
    const float* W2     = (const float*)d_in[10];
    const float* b2     = (const float*)d_in[11];
    const float* W3     = (const float*)d_in[12];
    const float* b3     = (const float*)d_in[13];
    const float* W4     = (const float*)d_in[14];
    const float* b4     = (const float*)d_in[15];
    const float* W5     = (const float*)d_in[16];
    const float* b5     = (const float*)d_in[17];

    char* ws = (char*)d_ws;
    uint8_t* codes = (uint8_t*)ws;  ws += (size_t)16 << 20;
    char* ping = ws;                ws += 18874368;   // XT(6.29MB) + XR(12.58MB)
    char* pong = ws;                ws += 18874368;
    float* h0  = (float*)ws;        ws += 103168;
    float* hA  = (float*)ws;        ws += 128000;
    float* hB  = (float*)ws;        ws += 128000;

    uint16_t* XTp = (uint16_t*)ping; float* XRp = (float*)(ping + 6291456);
    uint16_t* XTq = (uint16_t*)pong; float* XRq = (float*)(pong + 6291456);

    hipMemsetAsync(h0, 0, (size_t)NB * LIN_IN * 4, stream);

    codes_kernel<<<2048, 256, 0, stream>>>(sM, codes, 16 * 1024 * 1024 / 4);
    labels_to_xt<<<dim3(16, 4), 256, 0, stream>>>(labels, XTq, XRq);

    wlc_gemm<<<dim3(16, 2, 16), 256, 0, stream>>>(XTq, XRq, XTp, XRp, codes, K1, 0, 1, 1, 2, 0);
    wlc_gemm<<<dim3(16, 2, 16), 256, 0, stream>>>(XTp, XRp, XTq, XRq, codes, K1, 1, 0, 2, 2, 1);
    wlc_gemm<<<dim3(16, 4, 16), 256, 0, stream>>>(XTq, XRq, XTp, XRp, codes, K2, 0, 1, 2, 4, 0);
    wlc_gemm<<<dim3(16, 4, 16), 256, 0, stream>>>(XTp, XRp, XTq, XRq, codes, K2, 1, 0, 4, 4, 1);

    spp_max_kernel<<<6160, 256, 0, stream>>>(XRq, h0);
    conv_pool_strip<<<dim3(30, 2, 16), 256, 0, stream>>>(sM, cw1, cb1, cw2, cb2, h0);
    stru_div_kernel<<<5, 256, 0, stream>>>(h0);

    fc_kernel<<<500, 256, 0, stream>>>(h0, W1, b1, hA, LIN_IN, 2000, 1);
    fc_kernel<<<500, 256, 0, stream>>>(hA, W2, b2, hB, 2000, 2000, 1);
    fc_kernel<<<500, 256, 0, stream>>>(hB, W3, b3, hA, 2000, 2000, 1);
    fc_kernel<<<500, 256, 0, stream>>>(hA, W4, b4, hB, 2000, 2000, 1);
    fc_kernel<<<1,   256, 0, stream>>>(hB, W5, b5, (float*)d_out, 2000, 2, 0);
}

// Round 6
// 480.792 us; speedup vs baseline: 1.0250x; 1.0250x over previous
//
#include <hip/hip_runtime.h>
#include <stdint.h>

#define NN 1024
#define FF 35
#define LIN_IN 1610
#define NB 16

typedef short short8 __attribute__((ext_vector_type(8)));
typedef float f32x4 __attribute__((ext_vector_type(4)));

__device__ __forceinline__ float leakyf(float x) { return fmaxf(x, 0.01f * x); }
__device__ __forceinline__ uint16_t to_bf16(float v) {
    return (uint16_t)((__float_as_uint(v) + 0x8000u) >> 16);
}

// ---------------------------------------------------------------- codes: s(float 0..4) -> u8
__global__ __launch_bounds__(256)
void codes_kernel(const float* __restrict__ s, uint8_t* __restrict__ codes, int n4) {
    int i = blockIdx.x * 256 + threadIdx.x;
    for (; i < n4; i += gridDim.x * 256) {
        float4 v = ((const float4*)s)[i];
        uchar4 c;
        c.x = (uint8_t)v.x; c.y = (uint8_t)v.y; c.z = (uint8_t)v.z; c.w = (uint8_t)v.w;
        ((uchar4*)codes)[i] = c;
    }
}

// ---------------------------------------------------------------- labels -> XT0 bf16 [16][48][1024] + XR0 f32
__global__ __launch_bounds__(256)
void labels_to_xt(const float* __restrict__ labels, uint16_t* __restrict__ XT0,
                  float* __restrict__ XR0)
{
    __shared__ float buf[256 * FF];
    const int s = blockIdx.x;
    const int i0 = blockIdx.y * 256;
    const float* src = labels + ((size_t)s * NN + i0) * FF;
    for (int t = threadIdx.x; t < 256 * FF; t += 256) buf[t] = src[t];
    __syncthreads();
    for (int f = 0; f < 48; ++f) {
        const int ii = threadIdx.x;
        float v = (f < FF) ? buf[ii * FF + f] : 0.f;
        size_t o = ((size_t)s * 48 + f) * 1024 + i0 + ii;
        XR0[o] = v;
        XT0[o] = to_bf16(v);
    }
}

// ---------------------------------------------------------------- one-hot A-fragment expansion
// Borrow-free per-byte zero detect (exact per-byte mask).
__device__ __forceinline__ short8 expand_onehot(uint2 cd, uint32_t dupK) {
    union { uint32_t u[4]; short8 v; } r;
#pragma unroll
    for (int h = 0; h < 2; ++h) {
        uint32_t d = h ? cd.y : cd.x;
        uint32_t y = d ^ dupK;
        uint32_t m = (~(((y & 0x7F7F7F7Fu) + 0x7F7F7F7Fu) | y)) & 0x80808080u;
        uint32_t m2 = m >> 7;                               // 0x01 at matched bytes
        r.u[h * 2 + 0] = ((m2 & 0xFFu) | ((m2 & 0xFF00u) << 8)) * 0x3F80u;
        r.u[h * 2 + 1] = (((m2 >> 16) & 0xFFu) | ((m2 >> 8) & 0xFF0000u)) * 0x3F80u;
    }
    return r.v;
}

// ---------------------------------------------------------------- WLC step as MFMA GEMM
// 64(M=i) x 96(N=2 chout x 48f) per block; A-expansion amortized over 6 nf.
// Register prefetch: next j-tile's staging + code bytes load during MFMA phase.
__global__ __launch_bounds__(256, 2)
void wlc_gemm(const uint16_t* __restrict__ XT_in, const float* __restrict__ XR_in,
              uint16_t* __restrict__ XT_out, float* __restrict__ XR_out,
              const uint8_t* __restrict__ codes, const float* __restrict__ Kg,
              int t, int shift, int nch_in, int nch_out, int do_leaky)
{
    __shared__ __align__(16) uint16_t xs[96 * 64];

    const int s   = blockIdx.z;
    const int mt  = blockIdx.x;
    const int nt  = blockIdx.y;
    const int tid = threadIdx.x;
    const int wid = tid >> 6;
    const int lane = tid & 63;
    const int i0 = mt * 64;

    // staging: 96 rows x 64 bf16 = 768 16B-units, 3 per thread; XOR-swizzled dest
    const uint16_t* srcp[3];
    uint16_t* dstp[3];
#pragma unroll
    for (int it = 0; it < 3; ++it) {
        int u = it * 256 + tid;
        int r = u >> 3, c8 = u & 7;
        int hi = (r >= 48);
        int chout_r = nt * 2 + hi;
        int f_r = r - 48 * hi;
        int inch_r = chout_r >> shift;
        srcp[it] = XT_in + (((size_t)s * nch_in + inch_r) * 48 + f_r) * 1024 + c8 * 8;
        dstp[it] = &xs[r * 64 + ((c8 ^ (r & 7)) * 8)];
    }

    const uint8_t* cbase = codes + ((size_t)s << 20)
        + (size_t)(i0 + wid * 16 + (lane & 15)) * 1024 + ((lane >> 4) << 3);

    f32x4 acc[4][6];
#pragma unroll
    for (int k = 0; k < 4; ++k)
#pragma unroll
        for (int nf = 0; nf < 6; ++nf) acc[k][nf] = (f32x4){0.f, 0.f, 0.f, 0.f};

    // prefetch tile 0
    uint4 pre[3];
#pragma unroll
    for (int it = 0; it < 3; ++it) pre[it] = *(const uint4*)(srcp[it]);
    uint2 pcd0 = *(const uint2*)(cbase);
    uint2 pcd1 = *(const uint2*)(cbase + 32);

    for (int jt = 0; jt < 16; ++jt) {
        __syncthreads();                        // previous tile's reads done
#pragma unroll
        for (int it = 0; it < 3; ++it) *(uint4*)dstp[it] = pre[it];
        __syncthreads();

        const uint2 cd0 = pcd0, cd1 = pcd1;
        if (jt < 15) {                          // prefetch next tile during compute
            const int j1 = (jt + 1) * 64;
#pragma unroll
            for (int it = 0; it < 3; ++it) pre[it] = *(const uint4*)(srcp[it] + j1);
            pcd0 = *(const uint2*)(cbase + j1);
            pcd1 = *(const uint2*)(cbase + j1 + 32);
        }

        short8 bfr[6][2];
#pragma unroll
        for (int nf = 0; nf < 6; ++nf)
#pragma unroll
            for (int kk = 0; kk < 2; ++kk) {
                int n = nf * 16 + (lane & 15);
                int c8 = kk * 4 + (lane >> 4);
                bfr[nf][kk] = *(const short8*)&xs[n * 64 + ((c8 ^ (n & 7)) * 8)];
            }

#pragma unroll
        for (int k = 0; k < 4; ++k) {
            const uint32_t dupK = 0x01010101u * (k + 1);
#pragma unroll
            for (int kk = 0; kk < 2; ++kk) {
                short8 af = expand_onehot(kk ? cd1 : cd0, dupK);
#pragma unroll
                for (int nf = 0; nf < 6; ++nf)
                    acc[k][nf] = __builtin_amdgcn_mfma_f32_16x16x32_bf16(
                        af, bfr[nf][kk], acc[k][nf], 0, 0, 0);
            }
        }
    }

    float sc[4][6];
#pragma unroll
    for (int nf = 0; nf < 6; ++nf) {
        int fnl = (nf % 3) * 16 + (lane & 15);
        int chout = nt * 2 + nf / 3;
        int kch = chout & 1;
#pragma unroll
        for (int k = 0; k < 4; ++k)
            sc[k][nf] = (fnl < FF) ? Kg[((kch * 2 + t) * 4 + k) * FF + fnl] : 0.f;
    }

#pragma unroll
    for (int nf = 0; nf < 6; ++nf) {
        int fnl = (nf % 3) * 16 + (lane & 15);
        int chout = nt * 2 + nf / 3;
        int inch = chout >> shift;
        int irow = i0 + wid * 16 + ((lane >> 4) << 2);
        f32x4 rr = sc[0][nf] * acc[0][nf];
        rr += sc[1][nf] * acc[1][nf];
        rr += sc[2][nf] * acc[2][nf];
        rr += sc[3][nf] * acc[3][nf];
        size_t rb = (((size_t)s * nch_in + inch) * 48 + fnl) * 1024 + irow;
        float4 rd = *(const float4*)&XR_in[rb];
        float y0 = rr.x + rd.x, y1 = rr.y + rd.y, y2 = rr.z + rd.z, y3 = rr.w + rd.w;
        if (do_leaky) { y0 = leakyf(y0); y1 = leakyf(y1); y2 = leakyf(y2); y3 = leakyf(y3); }
        size_t ob = (((size_t)s * nch_out + chout) * 48 + fnl) * 1024 + irow;
        *(float4*)&XR_out[ob] = make_float4(y0, y1, y2, y3);
        ushort4 bv;
        bv.x = to_bf16(y0); bv.y = to_bf16(y1); bv.z = to_bf16(y2); bv.w = to_bf16(y3);
        *(ushort4*)&XT_out[ob] = bv;
    }
}

// ---------------------------------------------------------------- spp max over c2 (layout [s][c][48][1024])
__global__ __launch_bounds__(256)
void spp_max_kernel(const float* __restrict__ xr4, float* __restrict__ h0)
{
    const int gw   = (blockIdx.x * 256 + threadIdx.x) >> 6;
    const int lane = threadIdx.x & 63;
    if (gw >= NB * 4 * 385) return;
    const int s    = gw / (4 * 385);
    int rem        = gw - s * (4 * 385);
    const int c    = rem / 385;
    const int cell = rem - c * 385;

    int p1 = 1, base = 0;
    while (p1 < 10 && cell >= base + p1 * p1) { base += p1 * p1; ++p1; }
    const int ci = cell - base;

    int kh = (NN + p1 - 1) / p1;  int ph = kh * p1 - NN; if (ph * 2 > kh) ph = kh / 2;
    int kw = (FF + p1 - 1) / p1;  int pw = kw * p1 - FF; if (pw * 2 > kw) pw = kw / 2;
    const int ow = (FF + 2 * pw - kw) / kw + 1;
    const int oh = (NN + 2 * ph - kh) / kh + 1;
    if (ci >= oh * ow) return;

    const int r = ci / ow, cw = ci - r * ow;
    int r0 = r * kh - ph;  int r1 = r0 + kh; if (r1 > NN) r1 = NN; if (r0 < 0) r0 = 0;
    int c0 = cw * kw - pw; int c1 = c0 + kw; if (c1 > FF) c1 = FF; if (c0 < 0) c0 = 0;

    const float* bp = xr4 + ((size_t)s * 4 + c) * (48 * 1024);
    float m = -3.402823466e38f;
    for (int ff = c0; ff < c1; ++ff) {
        const float* rowp = bp + (size_t)ff * 1024;
        for (int ii = r0 + lane; ii < r1; ii += 64) m = fmaxf(m, rowp[ii]);
    }
#pragma unroll
    for (int o = 32; o >= 1; o >>= 1) m = fmaxf(m, __shfl_xor(m, o, 64));
    if (lane == 0) h0[(size_t)s * LIN_IN + c * 385 + cell] = m;
}

// ---------------------------------------------------------------- fused conv1+conv2+avg pools, 17-row strips
// 60 strips x 17 rows; all row-bin boundaries (340=20*17, 510=30*17, 680=40*17)
// are strip-aligned. 255 threads x 4 cols, round-4 inner loop. Avg-pool
// divisors folded into the final atomics (no stru_div pass).
__global__ __launch_bounds__(256, 2)
void conv_pool_strip(const float* __restrict__ sM,
                     const float* __restrict__ cw1, const float* __restrict__ cb1,
                     const float* __restrict__ cw2, const float* __restrict__ cb2,
                     float* __restrict__ h0)
{
    __shared__ float bins[30];   // [5ch][b]: b=0 p1, 1..2 p2 col-bins, 3..5 p3 col-bins
    const int ss   = blockIdx.x;     // strip 0..59
    const int simg = blockIdx.y;     // image
    const int tid  = threadIdx.x;
    const int lane = tid & 63;
    const int r0   = ss * 17;
    const int rb2  = ss / 30;
    const int rb3  = ss / 20;

    if (tid < 30) bins[tid] = 0.f;
    __syncthreads();

    const int colbase = (tid < 255) ? tid * 4 : 254 * 4;
    const float* sp = sM + (size_t)simg * (NN * NN) + colbase;

    float w1r[18], w2r[90], b1r[2], b2r[5];
#pragma unroll
    for (int i = 0; i < 18; ++i) w1r[i] = cw1[i];
#pragma unroll
    for (int i = 0; i < 90; ++i) w2r[i] = cw2[i];
    b1r[0] = cb1[0]; b1r[1] = cb1[1];
#pragma unroll
    for (int i = 0; i < 5; ++i) b2r[i] = cb2[i];

    float sw[3][8];
    float z1w[3][2][6];
    float acc[5][4];
#pragma unroll
    for (int o = 0; o < 5; ++o)
#pragma unroll
        for (int j = 0; j < 4; ++j) acc[o][j] = 0.f;

#define LOADROW(slot, rabs) do { \
    float4 v0 = *(const float4*)(sp + (size_t)(rabs) * NN); \
    float4 v1 = *(const float4*)(sp + (size_t)(rabs) * NN + 4); \
    sw[slot][0]=v0.x; sw[slot][1]=v0.y; sw[slot][2]=v0.z; sw[slot][3]=v0.w; \
    sw[slot][4]=v1.x; sw[slot][5]=v1.y; sw[slot][6]=v1.z; sw[slot][7]=v1.w; } while(0)

#define Z1ROW(P) do { \
    _Pragma("unroll") for (int ch = 0; ch < 2; ++ch) { \
      _Pragma("unroll") for (int jj = 0; jj < 6; ++jj) { \
        float a = b1r[ch]; \
        _Pragma("unroll") for (int dc = 0; dc < 3; ++dc) { \
            a += sw[((P)+2)%3][jj+dc] * w1r[ch*9+0+dc]; \
            a += sw[(P)%3    ][jj+dc] * w1r[ch*9+3+dc]; \
            a += sw[((P)+1)%3][jj+dc] * w1r[ch*9+6+dc]; } \
        z1w[((P)+2)%3][ch][jj] = leakyf(a); } } } while(0)

#define Z2ROW(P) do { \
    _Pragma("unroll") for (int o = 0; o < 5; ++o) { \
      _Pragma("unroll") for (int j = 0; j < 4; ++j) { \
        float a = b2r[o]; \
        _Pragma("unroll") for (int ich = 0; ich < 2; ++ich) { \
          _Pragma("unroll") for (int dc = 0; dc < 3; ++dc) { \
            a += z1w[(P)%3    ][ich][j+dc] * w2r[(o*2+ich)*9+0+dc]; \
            a += z1w[((P)+1)%3][ich][j+dc] * w2r[(o*2+ich)*9+3+dc]; \
            a += z1w[((P)+2)%3][ich][j+dc] * w2r[(o*2+ich)*9+6+dc]; } } \
        acc[o][j] += leakyf(a); } } } while(0)

    // prologue: s rows r0..r0+3, z1 rows r0,r0+1
    LOADROW(0, r0 + 0);
    LOADROW(1, r0 + 1);
    LOADROW(2, r0 + 2);
    Z1ROW(1);
    LOADROW(0, r0 + 3);
    Z1ROW(2);

#pragma unroll 1
    for (int rr = 0; rr < 15; rr += 3) {       // z2 rows 0..14
        LOADROW(1, r0 + rr + 4); Z1ROW(0); Z2ROW(0);
        LOADROW(2, r0 + rr + 5); Z1ROW(1); Z2ROW(1);
        LOADROW(0, r0 + rr + 6); Z1ROW(2); Z2ROW(2);
    }
    LOADROW(1, r0 + 19); Z1ROW(0); Z2ROW(0);   // z2 row 15
    LOADROW(2, r0 + 20); Z1ROW(1); Z2ROW(1);   // z2 row 16

#undef LOADROW
#undef Z1ROW
#undef Z2ROW

    if (tid == 255) {
#pragma unroll
        for (int o = 0; o < 5; ++o)
#pragma unroll
            for (int j = 0; j < 4; ++j) acc[o][j] = 0.f;
    }

    int cb2c[4], cb3c[4];
#pragma unroll
    for (int j = 0; j < 4; ++j) {
        int col = colbase + j;
        int a2 = col / 510; if (a2 > 1) a2 = 1;
        int a3 = col / 340; if (a3 > 2) a3 = 2;
        cb2c[j] = a2; cb3c[j] = a3;
    }

#pragma unroll
    for (int o = 0; o < 5; ++o) {
        float t1 = acc[o][0] + acc[o][1] + acc[o][2] + acc[o][3];
        float pa = 0.f, pb = 0.f, q0 = 0.f, q1 = 0.f, q2 = 0.f;
#pragma unroll
        for (int j = 0; j < 4; ++j) {
            float v = acc[o][j];
            if (cb2c[j] == 0) pa += v; else pb += v;
            if (cb3c[j] == 0) q0 += v; else if (cb3c[j] == 1) q1 += v; else q2 += v;
        }
#pragma unroll
        for (int d = 32; d >= 1; d >>= 1) {
            t1 += __shfl_xor(t1, d, 64);
            pa += __shfl_xor(pa, d, 64);
            pb += __shfl_xor(pb, d, 64);
            q0 += __shfl_xor(q0, d, 64);
            q1 += __shfl_xor(q1, d, 64);
            q2 += __shfl_xor(q2, d, 64);
        }
        if (lane == 0) {
            atomicAdd(&bins[o * 6 + 0], t1);
            atomicAdd(&bins[o * 6 + 1], pa);
            atomicAdd(&bins[o * 6 + 2], pb);
            atomicAdd(&bins[o * 6 + 3], q0);
            atomicAdd(&bins[o * 6 + 4], q1);
            atomicAdd(&bins[o * 6 + 5], q2);
        }
    }
    __syncthreads();
    if (tid < 30) {
        int o = tid / 6, b = tid % 6;
        int off; float scale;
        if (b == 0)      { off = 0;                         scale = 1.f / (1020.f * 1020.f); }
        else if (b <= 2) { off = 1 + rb2 * 2 + (b - 1);     scale = 1.f / (510.f * 510.f); }
        else             { off = 5 + rb3 * 3 + (b - 3);     scale = 1.f / (340.f * 340.f); }
        atomicAdd(h0 + (size_t)simg * LIN_IN + 1540 + o * 14 + off, bins[tid] * scale);
    }
}

// ---------------------------------------------------------------- FC: 2 outputs per wave, float2 loads
__global__ __launch_bounds__(256)
void fc_kernel(const float* __restrict__ in, const float* __restrict__ W,
               const float* __restrict__ bias, float* __restrict__ out,
               int K, int Nout, int do_leaky)
{
    const int wv = (blockIdx.x * 256 + threadIdx.x) >> 6;
    const int lane = threadIdx.x & 63;
    const int o0 = wv * 2;
    if (o0 >= Nout) return;
    const int K2 = K >> 1;
    const float2* w0 = (const float2*)(W + (size_t)o0 * K);
    const float2* w1 = (const float2*)(W + (size_t)(o0 + 1) * K);
    float acc0[16], acc1[16];
#pragma unroll
    for (int b = 0; b < 16; ++b) { acc0[b] = 0.f; acc1[b] = 0.f; }
    for (int k0 = 0; k0 < K2; k0 += 64) {
        const int kk = k0 + lane;
        const bool in_r = kk < K2;
        const float2 a = in_r ? w0[kk] : make_float2(0.f, 0.f);
        const float2 c = in_r ? w1[kk] : make_float2(0.f, 0.f);
#pragma unroll
        for (int b = 0; b < 16; ++b) {
            const float2 h = in_r ? *(const float2*)(in + (size_t)b * K + kk * 2)
                                  : make_float2(0.f, 0.f);
            acc0[b] += a.x * h.x + a.y * h.y;
            acc1[b] += c.x * h.x + c.y * h.y;
        }
    }
    float r0 = 0.f, r1 = 0.f;
#pragma unroll
    for (int b = 0; b < 16; ++b) {
        float v = acc0[b];
#pragma unroll
        for (int od = 32; od >= 1; od >>= 1) v += __shfl_xor(v, od, 64);
        if (lane == b) r0 = v;
        float u = acc1[b];
#pragma unroll
        for (int od = 32; od >= 1; od >>= 1) u += __shfl_xor(u, od, 64);
        if (lane == b + 16) r1 = u;
    }
    if (lane < 16) {
        const float y = r0 + bias[o0];
        out[(size_t)lane * Nout + o0] = do_leaky ? leakyf(y) : y;
    } else if (lane < 32) {
        const float y = r1 + bias[o0 + 1];
        out[(size_t)(lane - 16) * Nout + o0 + 1] = do_leaky ? leakyf(y) : y;
    }
}

// ---------------------------------------------------------------- launch
extern "C" void kernel_launch(void* const* d_in, const int* in_sizes, int n_in,
                              void* d_out, int out_size, void* d_ws, size_t ws_size,
                              hipStream_t stream)
{
    const float* labels = (const float*)d_in[0];
    const float* sM     = (const float*)d_in[1];
    const float* K1     = (const float*)d_in[2];
    const float* K2     = (const float*)d_in[3];
    const float* cw1    = (const float*)d_in[4];
    const float* cb1    = (const float*)d_in[5];
    const float* cw2    = (const float*)d_in[6];
    const float* cb2    = (const float*)d_in[7];
    const float* W1     = (const float*)d_in[8];
    const float* b1     = (const float*)d_in[9];
    const float* W2     = (const float*)d_in[10];
    const float* b2     = (const float*)d_in[11];
    const float* W3     = (const float*)d_in[12];
    const float* b3     = (const float*)d_in[13];
    const float* W4     = (const float*)d_in[14];
    const float* b4     = (const float*)d_in[15];
    const float* W5     = (const float*)d_in[16];
    const float* b5     = (const float*)d_in[17];

    char* ws = (char*)d_ws;
    uint8_t* codes = (uint8_t*)ws;  ws += (size_t)16 << 20;
    char* ping = ws;                ws += 18874368;   // XT(6.29MB) + XR(12.58MB)
    char* pong = ws;                ws += 18874368;
    float* h0  = (float*)ws;        ws += 103168;
    float* hA  = (float*)ws;        ws += 128000;
    float* hB  = (float*)ws;        ws += 128000;

    uint16_t* XTp = (uint16_t*)ping; float* XRp = (float*)(ping + 6291456);
    uint16_t* XTq = (uint16_t*)pong; float* XRq = (float*)(pong + 6291456);

    hipMemsetAsync(h0, 0, (size_t)NB * LIN_IN * 4, stream);

    codes_kernel<<<2048, 256, 0, stream>>>(sM, codes, 16 * 1024 * 1024 / 4);
    labels_to_xt<<<dim3(16, 4), 256, 0, stream>>>(labels, XTq, XRq);

    wlc_gemm<<<dim3(16, 1, 16), 256, 0, stream>>>(XTq, XRq, XTp, XRp, codes, K1, 0, 1, 1, 2, 0);
    wlc_gemm<<<dim3(16, 1, 16), 256, 0, stream>>>(XTp, XRp, XTq, XRq, codes, K1, 1, 0, 2, 2, 1);
    wlc_gemm<<<dim3(16, 2, 16), 256, 0, stream>>>(XTq, XRq, XTp, XRp, codes, K2, 0, 1, 2, 4, 0);
    wlc_gemm<<<dim3(16, 2, 16), 256, 0, stream>>>(XTp, XRp, XTq, XRq, codes, K2, 1, 0, 4, 4, 1);

    spp_max_kernel<<<6160, 256, 0, stream>>>(XRq, h0);
    conv_pool_strip<<<dim3(60, 16), 256, 0, stream>>>(sM, cw1, cb1, cw2, cb2, h0);

    fc_kernel<<<250, 256, 0, stream>>>(h0, W1, b1, hA, LIN_IN, 2000, 1);
    fc_kernel<<<250, 256, 0, stream>>>(hA, W2, b2, hB, 2000, 2000, 1);
    fc_kernel<<<250, 256, 0, stream>>>(hB, W3, b3, hA, 2000, 2000, 1);
    fc_kernel<<<250, 256, 0, stream>>>(hA, W4, b4, hB, 2000, 2000, 1);
    fc_kernel<<<1,   256, 0, stream>>>(hB, W5, b5, (float*)d_out, 2000, 2, 0);
}